// Round 12
// baseline (107.301 us; speedup 1.0000x reference)
//
#include <hip/hip_runtime.h>
#include <math.h>

// Problem constants (from reference)
constexpr int Hr = 64;
constexpr int Wr = 2048;
constexpr int Hb = 512;
constexpr int Wb = 512;
constexpr int B  = 4;
constexpr int C  = 64;
constexpr int BC = B * C;            // 256 channels
constexpr int NPIX = Hb * Wb;        // 262144 pixels

constexpr int T = 8192;              // pixels per tile (per block)
constexpr int G = 8;                 // channels per block
constexpr int NTILE = NPIX / T;      // 32
constexpr int NCG   = BC / G;        // 32

typedef float f32x4 __attribute__((ext_vector_type(4)));

// R12 = R4 verbatim + mirror store of each result into d_ws (same offsets).
// DIAGNOSTIC: marginal cost of +268 MB HBM writes discriminates
//   H1 (kernel at ~7 TB/s write floor + ~17us fixed overhead): delta ~ +40us
//   H2 (kernel store path capped ~4.7 TB/s):                   delta ~ +57us
// Output correctness is unaffected (d_ws is scratch).

__global__ __launch_bounds__(256) void rv2bev_fused(
    const float* __restrict__ rv,    // [B][C][Hr][Wr]
    float* __restrict__ out,         // [B][C][Hb][Wb]
    float* __restrict__ ws)          // scratch mirror (diagnostic)
{
    __shared__ float rowbuf[2][Wr];  // 2 x 8 KB, double-buffered averaged row

    const int tile = blockIdx.x;     // 0..31
    const int cg   = blockIdx.y;     // 0..31
    const int tid  = threadIdx.x;

    // ---- per-block px computation: 32 pixels/thread, kept in registers ----
    int   x0[32];
    float wx[32];
    {
        const float cs = 50.0f / 255.5f;                    // R_MAX / (Hb/2 - 0.5)
        const float c1 = 2047.0f / 6.28318530717958647692f; // (Wr-1)/2pi
        const float c2 = 2047.0f / 2048.0f;                 // (Wr-1)/Wr
        #pragma unroll
        for (int k = 0; k < 8; ++k) {
            #pragma unroll
            for (int j = 0; j < 4; ++j) {
                const int n  = tile * T + (tid + k * 256) * 4 + j;  // global pixel
                const float y = ((float)(n >> 9)  - 255.5f) * cs;
                const float x = ((float)(n & 511) - 255.5f) * cs;
                float phi = atan2f(y, x);
                phi = (phi < 0.0f) ? phi + 6.28318530717958647692f : phi;
                const float px = (2047.0f - phi * c1) * c2;   // in (0, 2046.01)
                const float fx = floorf(px);
                x0[k * 4 + j] = (int)fx;                      // <= 2046
                wx[k * 4 + j] = px - fx;
            }
        }
    }

    // base of row 31, channel cg*G
    const float* rvb = rv + (size_t)(cg * G) * (Hr * Wr) + (size_t)31 * Wr;

    f32x4 sa0, sa1, sb0, sb1;        // staged rows for next channel

    // ---- prologue: stage channel 0 into rowbuf[0] ----
    {
        const f32x4* r31 = (const f32x4*)rvb;
        const f32x4* r32 = (const f32x4*)(rvb + Wr);
        sa0 = r31[tid]; sa1 = r31[tid + 256];
        sb0 = r32[tid]; sb1 = r32[tid + 256];
        f32x4* dst = (f32x4*)rowbuf[0];
        dst[tid]       = sa0 * 0.5f + sb0 * 0.5f;
        dst[tid + 256] = sa1 * 0.5f + sb1 * 0.5f;
    }

    for (int c = 0; c < G; ++c) {
        // T14 issue-early: launch next channel's global loads before the barrier
        if (c + 1 < G) {
            const float* chb = rvb + (size_t)(c + 1) * (Hr * Wr);
            const f32x4* r31 = (const f32x4*)chb;
            const f32x4* r32 = (const f32x4*)(chb + Wr);
            sa0 = r31[tid]; sa1 = r31[tid + 256];
            sb0 = r32[tid]; sb1 = r32[tid + 256];
        }
        __syncthreads();             // rowbuf[c&1] staged & prior gathers done

        const float* __restrict__ row = rowbuf[c & 1];
        const size_t obase = (size_t)(cg * G + c) * NPIX + (size_t)tile * T;
        f32x4* out4 = (f32x4*)(out + obase);
        f32x4* ws4  = (f32x4*)(ws  + obase);
        #pragma unroll
        for (int k = 0; k < 8; ++k) {
            f32x4 r;
            #pragma unroll
            for (int j = 0; j < 4; ++j) {
                const int i = k * 4 + j;
                const float w = wx[i];
                r[j] = row[x0[i]] * (1.0f - w) + row[x0[i] + 1] * w;
            }
            __builtin_nontemporal_store(r, out4 + tid + k * 256);
            __builtin_nontemporal_store(r, ws4 + tid + k * 256);   // +268 MB probe
        }

        // write-late: LDS write of next channel after this channel's gathers
        if (c + 1 < G) {
            f32x4* dst = (f32x4*)rowbuf[(c + 1) & 1];
            dst[tid]       = sa0 * 0.5f + sb0 * 0.5f;
            dst[tid + 256] = sa1 * 0.5f + sb1 * 0.5f;
        }
    }
}

extern "C" void kernel_launch(void* const* d_in, const int* in_sizes, int n_in,
                              void* d_out, int out_size, void* d_ws, size_t ws_size,
                              hipStream_t stream) {
    const float* rv_feat = (const float*)d_in[0];
    // d_in[1] (ref_bev) is unused by the reference computation.
    float* out = (float*)d_out;
    float* ws  = (float*)d_ws;       // 268 MB mirror region (ws_size ~ 1 GiB)

    rv2bev_fused<<<dim3(NTILE, NCG), dim3(256), 0, stream>>>(rv_feat, out, ws);
}